// Round 13
// baseline (87.260 us; speedup 1.0000x reference)
//
#include <hip/hip_runtime.h>

#define BB 8
#define SS 4096
#define DD 256
#define HH 1024
#define VOCAB 32000
#define NCH 128    // chunks per batch for esum/u passes (32 tokens each)
#define NLB 4000   // k_logits blocks; wave w owns batches 2w,2w+1; 8 rows/block

typedef float v2f __attribute__((ext_vector_type(2)));
typedef float v4f __attribute__((ext_vector_type(4)));

// ws layout (floats), no zero-init needed:
//   part_esum : [B][NCH][D] @ 0        (262144)
//   part_u    : [B][NCH][D] @ 262144   (262144)
//   a         : [B][D]      @ 524288   (2048)
//   h         : [B][H]      @ 526336   (8192)
//   spart     : [B][NLB][2] @ 534528   (64000)

// Pass 1: part_esum[b,chunk,d] = sum over 32 tokens of (x!=0 ? emb[x,d] : 0)
__global__ __launch_bounds__(256) void k_esum(const int* __restrict__ x,
        const float* __restrict__ emb, float* __restrict__ part_esum) {
    __shared__ int toks[32];
    const int b = blockIdx.y, chunk = blockIdx.x, tid = threadIdx.x;
    if (tid < 32) toks[tid] = x[b * SS + chunk * 32 + tid];
    __syncthreads();
    float acc[8];
    #pragma unroll
    for (int j = 0; j < 8; ++j) acc[j] = 0.f;
    for (int t = 0; t < 32; t += 8) {
        int tk[8];
        #pragma unroll
        for (int j = 0; j < 8; ++j) tk[j] = toks[t + j];
        #pragma unroll
        for (int j = 0; j < 8; ++j)
            if (tk[j]) acc[j] += emb[tk[j] * DD + tid];
    }
    part_esum[(b * NCH + chunk) * DD + tid] =
        ((acc[0] + acc[1]) + (acc[2] + acc[3])) + ((acc[4] + acc[5]) + (acc[6] + acc[7]));
}

// qa: es = reduce(part_esum) [wave-strided float4]; qs = wq@es [wave-per-row, 8 in flight];
//     a = sum_e qs[e]*wk[e,:] [accumulate-of-rows, 4 accumulators, LDS combine]
__global__ __launch_bounds__(256) void k_qa(const float* __restrict__ part_esum,
        const float* __restrict__ wq, const float* __restrict__ wk,
        float* __restrict__ a) {
    const int b = blockIdx.x, tid = threadIdx.x, wid = tid >> 6, lane = tid & 63;
    __shared__ __align__(16) float red[4][DD];
    __shared__ __align__(16) float es[DD];
    __shared__ __align__(16) float qs[DD];
    {
        const v4f* p = (const v4f*)(part_esum + (size_t)b * NCH * DD) + lane;
        v4f s0 = 0.f, s1 = 0.f, s2 = 0.f, s3 = 0.f;
        #pragma unroll
        for (int k = 0; k < 32; k += 4) {
            s0 += p[(wid + 4 * (k + 0)) * 64];
            s1 += p[(wid + 4 * (k + 1)) * 64];
            s2 += p[(wid + 4 * (k + 2)) * 64];
            s3 += p[(wid + 4 * (k + 3)) * 64];
        }
        ((v4f*)red[wid])[lane] = (s0 + s1) + (s2 + s3);
    }
    __syncthreads();
    es[tid] = (red[0][tid] + red[1][tid]) + (red[2][tid] + red[3][tid]);
    __syncthreads();
    {
        const v4f es4 = ((const v4f*)es)[lane];
        for (int r0 = 0; r0 < 64; r0 += 8) {
            float dp[8];
            #pragma unroll
            for (int j = 0; j < 8; ++j) {
                const v4f w4 = ((const v4f*)(wq + (size_t)(wid * 64 + r0 + j) * DD))[lane];
                const v4f m = w4 * es4;
                dp[j] = (m.x + m.y) + (m.z + m.w);
            }
            #pragma unroll
            for (int off = 32; off; off >>= 1) {
                #pragma unroll
                for (int j = 0; j < 8; ++j) dp[j] += __shfl_xor(dp[j], off, 64);
            }
            if (lane < 8) qs[wid * 64 + r0 + lane] = dp[lane];
        }
    }
    __syncthreads();
    {
        v4f p0 = 0.f, p1 = 0.f, p2 = 0.f, p3 = 0.f;
        #pragma unroll 4
        for (int k = 0; k < 64; k += 4) {
            const int e0 = wid + 4 * k, e1 = e0 + 4, e2 = e0 + 8, e3 = e0 + 12;
            p0 += qs[e0] * ((const v4f*)(wk + (size_t)e0 * DD))[lane];
            p1 += qs[e1] * ((const v4f*)(wk + (size_t)e1 * DD))[lane];
            p2 += qs[e2] * ((const v4f*)(wk + (size_t)e2 * DD))[lane];
            p3 += qs[e3] * ((const v4f*)(wk + (size_t)e3 * DD))[lane];
        }
        ((v4f*)red[wid])[lane] = (p0 + p1) + (p2 + p3);
    }
    __syncthreads();
    a[b * DD + tid] = (red[0][tid] + red[1][tid]) + (red[2][tid] + red[3][tid]);
}

// Pass 2: part_u[b,chunk,d] = sum over 32 tokens of (a[b]·e_s) e_s[d]; 8 tokens in flight
__global__ __launch_bounds__(256) void k_u(const int* __restrict__ x,
        const float* __restrict__ emb, const float* __restrict__ a,
        float* __restrict__ part_u) {
    const int b = blockIdx.y, chunk = blockIdx.x, tid = threadIdx.x;
    const int wid = tid >> 6, lane = tid & 63;
    __shared__ int toks[32];
    __shared__ __align__(16) float ured[4][DD];
    if (tid < 32) toks[tid] = x[b * SS + chunk * 32 + tid];
    __syncthreads();
    const float4 a4 = ((const float4*)(a + b * DD))[lane];
    float4 up = {0.f, 0.f, 0.f, 0.f};
    {
        int tok[8]; float4 e4[8]; float dp[8];
        #pragma unroll
        for (int j = 0; j < 8; ++j) tok[j] = toks[j * 4 + wid];
        #pragma unroll
        for (int j = 0; j < 8; ++j) {
            e4[j] = ((const float4*)(emb + tok[j] * DD))[lane];
            dp[j] = e4[j].x * a4.x + e4[j].y * a4.y + e4[j].z * a4.z + e4[j].w * a4.w;
        }
        #pragma unroll
        for (int off = 32; off; off >>= 1) {
            #pragma unroll
            for (int j = 0; j < 8; ++j) dp[j] += __shfl_xor(dp[j], off, 64);
        }
        #pragma unroll
        for (int j = 0; j < 8; ++j) {
            const float m = (tok[j] != 0) ? dp[j] : 0.f;
            up.x += m * e4[j].x; up.y += m * e4[j].y;
            up.z += m * e4[j].z; up.w += m * e4[j].w;
        }
    }
    ((float4*)ured[wid])[lane] = up;
    __syncthreads();
    part_u[(b * NCH + chunk) * DD + tid] =
        ured[0][tid] + ured[1][tid] + ured[2][tid] + ured[3][tid];
}

// Merged tail: block (g,b) reduces part_u -> us, vout = wv@us in LDS, then 32 h-rows.
__global__ __launch_bounds__(256) void k_vh(const float* __restrict__ part_u,
        const float* __restrict__ wv, const float* __restrict__ w1,
        const float* __restrict__ b1, float* __restrict__ h) {
    const int b = blockIdx.y, g = blockIdx.x, tid = threadIdx.x;
    const int wid = tid >> 6, lane = tid & 63;
    __shared__ __align__(16) float red[4][DD];
    __shared__ __align__(16) float us[DD];
    __shared__ __align__(16) float vo[DD];
    {
        const v4f* p = (const v4f*)(part_u + (size_t)b * NCH * DD) + lane;
        v4f s0 = 0.f, s1 = 0.f, s2 = 0.f, s3 = 0.f;
        #pragma unroll
        for (int k = 0; k < 32; k += 4) {
            s0 += p[(wid + 4 * (k + 0)) * 64];
            s1 += p[(wid + 4 * (k + 1)) * 64];
            s2 += p[(wid + 4 * (k + 2)) * 64];
            s3 += p[(wid + 4 * (k + 3)) * 64];
        }
        ((v4f*)red[wid])[lane] = (s0 + s1) + (s2 + s3);
    }
    __syncthreads();
    us[tid] = (red[0][tid] + red[1][tid]) + (red[2][tid] + red[3][tid]);
    __syncthreads();
    {
        const v4f u4 = ((const v4f*)us)[lane];
        for (int r0 = 0; r0 < 64; r0 += 8) {
            float dp[8];
            #pragma unroll
            for (int j = 0; j < 8; ++j) {
                const v4f w4 = ((const v4f*)(wv + (size_t)(wid * 64 + r0 + j) * DD))[lane];
                const v4f m = w4 * u4;
                dp[j] = (m.x + m.y) + (m.z + m.w);
            }
            #pragma unroll
            for (int off = 32; off; off >>= 1) {
                #pragma unroll
                for (int j = 0; j < 8; ++j) dp[j] += __shfl_xor(dp[j], off, 64);
            }
            if (lane < 8) vo[wid * 64 + r0 + lane] = dp[lane];
        }
    }
    __syncthreads();
    {
        const float4 v4 = ((const float4*)vo)[lane];
        const int rbase = g * 32 + wid * 8;
        float dp[8];
        #pragma unroll
        for (int r = 0; r < 8; ++r) {
            const float4 w4 = ((const float4*)(w1 + (size_t)(rbase + r) * DD))[lane];
            dp[r] = w4.x * v4.x + w4.y * v4.y + w4.z * v4.z + w4.w * v4.w;
        }
        #pragma unroll
        for (int off = 32; off; off >>= 1) {
            #pragma unroll
            for (int r = 0; r < 8; ++r) dp[r] += __shfl_xor(dp[r], off, 64);
        }
        if (lane < 8) h[b * HH + rbase + lane] = fmaxf(dp[lane] + b1[rbase + lane], 0.f);
    }
}

// logits: 4000 blocks x 8 rows; wave wid owns batches (2wid, 2wid+1); all 4 waves
// stream the same 8 w2 rows (dup reads served by L1). Fused softmax partials.
__global__ __launch_bounds__(256, 4) void k_logits(const float* __restrict__ h,
        const float* __restrict__ w2, const float* __restrict__ b2,
        float* __restrict__ out, float* __restrict__ spart) {
    const int tid = threadIdx.x, wid = tid >> 6, lane = tid & 63;
    const int half = lane >> 5;               // 0 -> batch 2wid, 1 -> batch 2wid+1
    v2f hp[16];
    #pragma unroll
    for (int c = 0; c < 4; ++c) {
        const float4 ta = ((const float4*)(h + (2 * wid)     * HH + c * 256))[lane];
        const float4 tb = ((const float4*)(h + (2 * wid + 1) * HH + c * 256))[lane];
        hp[c * 4 + 0] = (v2f){ta.x, tb.x};
        hp[c * 4 + 1] = (v2f){ta.y, tb.y};
        hp[c * 4 + 2] = (v2f){ta.z, tb.z};
        hp[c * 4 + 3] = (v2f){ta.w, tb.w};
    }
    float m_run = -1e30f, s_run = 0.f;
    #pragma unroll 2
    for (int r = 0; r < 8; ++r) {
        const int i = blockIdx.x + r * NLB;
        const float4* row = (const float4*)(w2 + (size_t)i * HH);
        v2f acc = (v2f){0.f, 0.f};
        #pragma unroll
        for (int c = 0; c < 4; ++c) {
            const float4 w = row[c * 64 + lane];
            acc += hp[c * 4 + 0] * w.x;
            acc += hp[c * 4 + 1] * w.y;
            acc += hp[c * 4 + 2] * w.z;
            acc += hp[c * 4 + 3] * w.w;
        }
        const float send = (half == 0) ? acc.y : acc.x;
        const float keep = (half == 0) ? acc.x : acc.y;
        float s = keep + __shfl_xor(send, 32, 64);
        s += __shfl_xor(s, 16, 64);
        s += __shfl_xor(s, 8, 64);
        s += __shfl_xor(s, 4, 64);
        s += __shfl_xor(s, 2, 64);
        s += __shfl_xor(s, 1, 64);
        if ((lane & 31) == 0) {
            const float lg = s + b2[i];
            out[(2 * wid + half) * VOCAB + i] = lg;
            const float mn = fmaxf(m_run, lg);
            s_run = s_run * __expf(m_run - mn) + __expf(lg - mn);
            m_run = mn;
        }
    }
    if ((lane & 31) == 0)
        ((v2f*)spart)[(2 * wid + half) * NLB + blockIdx.x] = (v2f){m_run, s_run};
}

// merge NLB partials per batch, then normalize the block's 1/16 slice of logits
__global__ __launch_bounds__(256) void k_norm(const float* __restrict__ spart,
        float* __restrict__ out) {
    const int b = blockIdx.y, seg = blockIdx.x, tid = threadIdx.x;
    __shared__ float rm[256], rs[256];
    const v2f* p = (const v2f*)spart + b * NLB;
    float m = -1e30f, s = 0.f;
    for (int idx = tid; idx < NLB; idx += 256) {
        const v2f t = p[idx];
        const float mn = fmaxf(m, t.x);
        s = s * __expf(m - mn) + t.y * __expf(t.x - mn);
        m = mn;
    }
    rm[tid] = m; rs[tid] = s;
    __syncthreads();
    for (int st = 128; st; st >>= 1) {
        if (tid < st) {
            const float m2 = rm[tid + st], s2 = rs[tid + st];
            const float mn = fmaxf(rm[tid], m2);
            rs[tid] = rs[tid] * __expf(rm[tid] - mn) + s2 * __expf(m2 - mn);
            rm[tid] = mn;
        }
        __syncthreads();
    }
    const float gm = rm[0], ginv = 1.f / rs[0];
    float* lg = out + b * VOCAB + seg * 2000;
    for (int i = tid; i < 2000; i += 256) lg[i] = __expf(lg[i] - gm) * ginv;
}

extern "C" void kernel_launch(void* const* d_in, const int* in_sizes, int n_in,
                              void* d_out, int out_size, void* d_ws, size_t ws_size,
                              hipStream_t stream) {
    const int*   x   = (const int*)d_in[0];
    const float* emb = (const float*)d_in[1];
    const float* wq  = (const float*)d_in[2];
    const float* wk  = (const float*)d_in[3];
    const float* wv  = (const float*)d_in[4];
    const float* w1  = (const float*)d_in[5];
    const float* b1  = (const float*)d_in[6];
    const float* w2  = (const float*)d_in[7];
    const float* b2  = (const float*)d_in[8];
    float* out = (float*)d_out;
    float* ws  = (float*)d_ws;

    float* part_esum = ws;               // 262144
    float* part_u    = ws + 262144;      // 262144
    float* a         = ws + 524288;      // 2048
    float* h         = ws + 526336;      // 8192
    float* spart     = ws + 534528;      // 64000

    k_esum<<<dim3(NCH, BB), 256, 0, stream>>>(x, emb, part_esum);
    k_qa<<<BB, 256, 0, stream>>>(part_esum, wq, wk, a);
    k_u<<<dim3(NCH, BB), 256, 0, stream>>>(x, emb, a, part_u);
    k_vh<<<dim3(32, BB), 256, 0, stream>>>(part_u, wv, w1, b1, h);
    k_logits<<<NLB, 256, 0, stream>>>(h, w2, b2, out, spart);
    k_norm<<<dim3(16, BB), 256, 0, stream>>>(spart, out);
}

// Round 14
// 83.262 us; speedup vs baseline: 1.0480x; 1.0480x over previous
//
#include <hip/hip_runtime.h>

#define BB 8
#define SS 4096
#define DD 256
#define HH 1024
#define VOCAB 32000
#define NCH 128    // chunks per batch for esum/u passes (32 tokens each)
#define NLB 2000   // k_logits blocks; wave w owns batches 2w,2w+1; 16 rows/block

typedef float v2f __attribute__((ext_vector_type(2)));
typedef float v4f __attribute__((ext_vector_type(4)));

// ws layout (floats), no zero-init needed:
//   part_esum : [B][NCH][D] @ 0        (262144)
//   part_u    : [B][NCH][D] @ 262144   (262144)
//   a         : [B][D]      @ 524288   (2048)
//   h         : [B][H]      @ 526336   (8192)
//   spart     : [B][NLB][2] @ 534528   (32000)

// Pass 1: part_esum[b,chunk,d] = sum over 32 tokens of (x!=0 ? emb[x,d] : 0)
__global__ __launch_bounds__(256) void k_esum(const int* __restrict__ x,
        const float* __restrict__ emb, float* __restrict__ part_esum) {
    __shared__ int toks[32];
    const int b = blockIdx.y, chunk = blockIdx.x, tid = threadIdx.x;
    if (tid < 32) toks[tid] = x[b * SS + chunk * 32 + tid];
    __syncthreads();
    float acc[8];
    #pragma unroll
    for (int j = 0; j < 8; ++j) acc[j] = 0.f;
    for (int t = 0; t < 32; t += 8) {
        int tk[8];
        #pragma unroll
        for (int j = 0; j < 8; ++j) tk[j] = toks[t + j];
        #pragma unroll
        for (int j = 0; j < 8; ++j)
            if (tk[j]) acc[j] += emb[tk[j] * DD + tid];
    }
    part_esum[(b * NCH + chunk) * DD + tid] =
        ((acc[0] + acc[1]) + (acc[2] + acc[3])) + ((acc[4] + acc[5]) + (acc[6] + acc[7]));
}

// qa: es = reduce(part_esum) [wave-strided float4]; qs = wq@es [wave-per-row, 8 in flight];
//     a = sum_e qs[e]*wk[e,:] [accumulate-of-rows, 4 accumulators, LDS combine]
__global__ __launch_bounds__(256) void k_qa(const float* __restrict__ part_esum,
        const float* __restrict__ wq, const float* __restrict__ wk,
        float* __restrict__ a) {
    const int b = blockIdx.x, tid = threadIdx.x, wid = tid >> 6, lane = tid & 63;
    __shared__ __align__(16) float red[4][DD];
    __shared__ __align__(16) float es[DD];
    __shared__ __align__(16) float qs[DD];
    {
        const v4f* p = (const v4f*)(part_esum + (size_t)b * NCH * DD) + lane;
        v4f s0 = 0.f, s1 = 0.f, s2 = 0.f, s3 = 0.f;
        #pragma unroll
        for (int k = 0; k < 32; k += 4) {
            s0 += p[(wid + 4 * (k + 0)) * 64];
            s1 += p[(wid + 4 * (k + 1)) * 64];
            s2 += p[(wid + 4 * (k + 2)) * 64];
            s3 += p[(wid + 4 * (k + 3)) * 64];
        }
        ((v4f*)red[wid])[lane] = (s0 + s1) + (s2 + s3);
    }
    __syncthreads();
    es[tid] = (red[0][tid] + red[1][tid]) + (red[2][tid] + red[3][tid]);
    __syncthreads();
    {
        const v4f es4 = ((const v4f*)es)[lane];
        for (int r0 = 0; r0 < 64; r0 += 8) {
            float dp[8];
            #pragma unroll
            for (int j = 0; j < 8; ++j) {
                const v4f w4 = ((const v4f*)(wq + (size_t)(wid * 64 + r0 + j) * DD))[lane];
                const v4f m = w4 * es4;
                dp[j] = (m.x + m.y) + (m.z + m.w);
            }
            #pragma unroll
            for (int off = 32; off; off >>= 1) {
                #pragma unroll
                for (int j = 0; j < 8; ++j) dp[j] += __shfl_xor(dp[j], off, 64);
            }
            if (lane < 8) qs[wid * 64 + r0 + lane] = dp[lane];
        }
    }
    __syncthreads();
    {
        v4f p0 = 0.f, p1 = 0.f, p2 = 0.f, p3 = 0.f;
        #pragma unroll 4
        for (int k = 0; k < 64; k += 4) {
            const int e0 = wid + 4 * k, e1 = e0 + 4, e2 = e0 + 8, e3 = e0 + 12;
            p0 += qs[e0] * ((const v4f*)(wk + (size_t)e0 * DD))[lane];
            p1 += qs[e1] * ((const v4f*)(wk + (size_t)e1 * DD))[lane];
            p2 += qs[e2] * ((const v4f*)(wk + (size_t)e2 * DD))[lane];
            p3 += qs[e3] * ((const v4f*)(wk + (size_t)e3 * DD))[lane];
        }
        ((v4f*)red[wid])[lane] = (p0 + p1) + (p2 + p3);
    }
    __syncthreads();
    a[b * DD + tid] = (red[0][tid] + red[1][tid]) + (red[2][tid] + red[3][tid]);
}

// Pass 2: part_u[b,chunk,d] = sum over 32 tokens of (a[b]·e_s) e_s[d]; 8 tokens in flight
__global__ __launch_bounds__(256) void k_u(const int* __restrict__ x,
        const float* __restrict__ emb, const float* __restrict__ a,
        float* __restrict__ part_u) {
    const int b = blockIdx.y, chunk = blockIdx.x, tid = threadIdx.x;
    const int wid = tid >> 6, lane = tid & 63;
    __shared__ int toks[32];
    __shared__ __align__(16) float ured[4][DD];
    if (tid < 32) toks[tid] = x[b * SS + chunk * 32 + tid];
    __syncthreads();
    const float4 a4 = ((const float4*)(a + b * DD))[lane];
    float4 up = {0.f, 0.f, 0.f, 0.f};
    {
        int tok[8]; float4 e4[8]; float dp[8];
        #pragma unroll
        for (int j = 0; j < 8; ++j) tok[j] = toks[j * 4 + wid];
        #pragma unroll
        for (int j = 0; j < 8; ++j) {
            e4[j] = ((const float4*)(emb + tok[j] * DD))[lane];
            dp[j] = e4[j].x * a4.x + e4[j].y * a4.y + e4[j].z * a4.z + e4[j].w * a4.w;
        }
        #pragma unroll
        for (int off = 32; off; off >>= 1) {
            #pragma unroll
            for (int j = 0; j < 8; ++j) dp[j] += __shfl_xor(dp[j], off, 64);
        }
        #pragma unroll
        for (int j = 0; j < 8; ++j) {
            const float m = (tok[j] != 0) ? dp[j] : 0.f;
            up.x += m * e4[j].x; up.y += m * e4[j].y;
            up.z += m * e4[j].z; up.w += m * e4[j].w;
        }
    }
    ((float4*)ured[wid])[lane] = up;
    __syncthreads();
    part_u[(b * NCH + chunk) * DD + tid] =
        ured[0][tid] + ured[1][tid] + ured[2][tid] + ured[3][tid];
}

// Merged tail: block (g,b) reduces part_u -> us, vout = wv@us in LDS, then 32 h-rows.
__global__ __launch_bounds__(256) void k_vh(const float* __restrict__ part_u,
        const float* __restrict__ wv, const float* __restrict__ w1,
        const float* __restrict__ b1, float* __restrict__ h) {
    const int b = blockIdx.y, g = blockIdx.x, tid = threadIdx.x;
    const int wid = tid >> 6, lane = tid & 63;
    __shared__ __align__(16) float red[4][DD];
    __shared__ __align__(16) float us[DD];
    __shared__ __align__(16) float vo[DD];
    {
        const v4f* p = (const v4f*)(part_u + (size_t)b * NCH * DD) + lane;
        v4f s0 = 0.f, s1 = 0.f, s2 = 0.f, s3 = 0.f;
        #pragma unroll
        for (int k = 0; k < 32; k += 4) {
            s0 += p[(wid + 4 * (k + 0)) * 64];
            s1 += p[(wid + 4 * (k + 1)) * 64];
            s2 += p[(wid + 4 * (k + 2)) * 64];
            s3 += p[(wid + 4 * (k + 3)) * 64];
        }
        ((v4f*)red[wid])[lane] = (s0 + s1) + (s2 + s3);
    }
    __syncthreads();
    us[tid] = (red[0][tid] + red[1][tid]) + (red[2][tid] + red[3][tid]);
    __syncthreads();
    {
        const v4f u4 = ((const v4f*)us)[lane];
        for (int r0 = 0; r0 < 64; r0 += 8) {
            float dp[8];
            #pragma unroll
            for (int j = 0; j < 8; ++j) {
                const v4f w4 = ((const v4f*)(wv + (size_t)(wid * 64 + r0 + j) * DD))[lane];
                const v4f m = w4 * u4;
                dp[j] = (m.x + m.y) + (m.z + m.w);
            }
            #pragma unroll
            for (int off = 32; off; off >>= 1) {
                #pragma unroll
                for (int j = 0; j < 8; ++j) dp[j] += __shfl_xor(dp[j], off, 64);
            }
            if (lane < 8) vo[wid * 64 + r0 + lane] = dp[lane];
        }
    }
    __syncthreads();
    {
        const float4 v4 = ((const float4*)vo)[lane];
        const int rbase = g * 32 + wid * 8;
        float dp[8];
        #pragma unroll
        for (int r = 0; r < 8; ++r) {
            const float4 w4 = ((const float4*)(w1 + (size_t)(rbase + r) * DD))[lane];
            dp[r] = w4.x * v4.x + w4.y * v4.y + w4.z * v4.z + w4.w * v4.w;
        }
        #pragma unroll
        for (int off = 32; off; off >>= 1) {
            #pragma unroll
            for (int r = 0; r < 8; ++r) dp[r] += __shfl_xor(dp[r], off, 64);
        }
        if (lane < 8) h[b * HH + rbase + lane] = fmaxf(dp[lane] + b1[rbase + lane], 0.f);
    }
}

// logits: wave wid owns batches (2wid, 2wid+1); all 4 waves stream the same 16 w2 rows.
__global__ __launch_bounds__(256, 4) void k_logits(const float* __restrict__ h,
        const float* __restrict__ w2, const float* __restrict__ b2,
        float* __restrict__ out, float* __restrict__ spart) {
    const int tid = threadIdx.x, wid = tid >> 6, lane = tid & 63;
    const int half = lane >> 5;               // 0 -> batch 2wid, 1 -> batch 2wid+1
    v2f hp[16];
    #pragma unroll
    for (int c = 0; c < 4; ++c) {
        const float4 ta = ((const float4*)(h + (2 * wid)     * HH + c * 256))[lane];
        const float4 tb = ((const float4*)(h + (2 * wid + 1) * HH + c * 256))[lane];
        hp[c * 4 + 0] = (v2f){ta.x, tb.x};
        hp[c * 4 + 1] = (v2f){ta.y, tb.y};
        hp[c * 4 + 2] = (v2f){ta.z, tb.z};
        hp[c * 4 + 3] = (v2f){ta.w, tb.w};
    }
    float m_run = -1e30f, s_run = 0.f;
    #pragma unroll 2
    for (int r = 0; r < 16; ++r) {
        const int i = blockIdx.x + r * NLB;
        const float4* row = (const float4*)(w2 + (size_t)i * HH);
        v2f acc = (v2f){0.f, 0.f};
        #pragma unroll
        for (int c = 0; c < 4; ++c) {
            const float4 w = row[c * 64 + lane];
            acc += hp[c * 4 + 0] * w.x;
            acc += hp[c * 4 + 1] * w.y;
            acc += hp[c * 4 + 2] * w.z;
            acc += hp[c * 4 + 3] * w.w;
        }
        const float send = (half == 0) ? acc.y : acc.x;
        const float keep = (half == 0) ? acc.x : acc.y;
        float s = keep + __shfl_xor(send, 32, 64);
        s += __shfl_xor(s, 16, 64);
        s += __shfl_xor(s, 8, 64);
        s += __shfl_xor(s, 4, 64);
        s += __shfl_xor(s, 2, 64);
        s += __shfl_xor(s, 1, 64);
        if ((lane & 31) == 0) {
            const float lg = s + b2[i];
            out[(2 * wid + half) * VOCAB + i] = lg;
            const float mn = fmaxf(m_run, lg);
            s_run = s_run * __expf(m_run - mn) + __expf(lg - mn);
            m_run = mn;
        }
    }
    if ((lane & 31) == 0)
        ((v2f*)spart)[(2 * wid + half) * NLB + blockIdx.x] = (v2f){m_run, s_run};
}

// merge NLB partials per batch, then normalize the block's 1/16 slice of logits
__global__ __launch_bounds__(256) void k_norm(const float* __restrict__ spart,
        float* __restrict__ out) {
    const int b = blockIdx.y, seg = blockIdx.x, tid = threadIdx.x;
    __shared__ float rm[256], rs[256];
    const v2f* p = (const v2f*)spart + b * NLB;
    float m = -1e30f, s = 0.f;
    for (int idx = tid; idx < NLB; idx += 256) {
        const v2f t = p[idx];
        const float mn = fmaxf(m, t.x);
        s = s * __expf(m - mn) + t.y * __expf(t.x - mn);
        m = mn;
    }
    rm[tid] = m; rs[tid] = s;
    __syncthreads();
    for (int st = 128; st; st >>= 1) {
        if (tid < st) {
            const float m2 = rm[tid + st], s2 = rs[tid + st];
            const float mn = fmaxf(rm[tid], m2);
            rs[tid] = rs[tid] * __expf(rm[tid] - mn) + s2 * __expf(m2 - mn);
            rm[tid] = mn;
        }
        __syncthreads();
    }
    const float gm = rm[0], ginv = 1.f / rs[0];
    float* lg = out + b * VOCAB + seg * 2000;
    for (int i = tid; i < 2000; i += 256) lg[i] = __expf(lg[i] - gm) * ginv;
}

extern "C" void kernel_launch(void* const* d_in, const int* in_sizes, int n_in,
                              void* d_out, int out_size, void* d_ws, size_t ws_size,
                              hipStream_t stream) {
    const int*   x   = (const int*)d_in[0];
    const float* emb = (const float*)d_in[1];
    const float* wq  = (const float*)d_in[2];
    const float* wk  = (const float*)d_in[3];
    const float* wv  = (const float*)d_in[4];
    const float* w1  = (const float*)d_in[5];
    const float* b1  = (const float*)d_in[6];
    const float* w2  = (const float*)d_in[7];
    const float* b2  = (const float*)d_in[8];
    float* out = (float*)d_out;
    float* ws  = (float*)d_ws;

    float* part_esum = ws;               // 262144
    float* part_u    = ws + 262144;      // 262144
    float* a         = ws + 524288;      // 2048
    float* h         = ws + 526336;      // 8192
    float* spart     = ws + 534528;      // 32000

    k_esum<<<dim3(NCH, BB), 256, 0, stream>>>(x, emb, part_esum);
    k_qa<<<BB, 256, 0, stream>>>(part_esum, wq, wk, a);
    k_u<<<dim3(NCH, BB), 256, 0, stream>>>(x, emb, a, part_u);
    k_vh<<<dim3(32, BB), 256, 0, stream>>>(part_u, wv, w1, b1, h);
    k_logits<<<NLB, 256, 0, stream>>>(h, w2, b2, out, spart);
    k_norm<<<dim3(16, BB), 256, 0, stream>>>(spart, out);
}